// Round 1
// 9398.422 us; speedup vs baseline: 1.3373x; 1.3373x over previous
//
#include <hip/hip_runtime.h>
#include <stdint.h>

// ---------------- problem constants ----------------
#define BSZ 64
#define TSEQ 512
#define KTAG 12
#define START_TAG 10
#define STOP_TAG 11

#define TPH 64   // timesteps per phase
#define NPH 8    // phases (TPH*NPH == TSEQ)
#define NWG 256
#define BLK 256

#define FIX_SCALE 4294967296.0
#define FIX_INV 2.3283064365386963e-10

// ---------------- workspace layout (bytes) ----------------
#define BAR_BYTES 4096
#define FEATS_OFF 4096
#define FEATS_BYTES (BSZ * TSEQ * KTAG * 8)        // 3145728
#define HBUF_OFF (FEATS_OFF + FEATS_BYTES)         // 3149824
#define HBUF_BYTES (2 * 512 * 128 * 4)             // 524288 (ping-pong h [u][ch])
#define CBUF_OFF (HBUF_OFF + HBUF_BYTES)           // 3674112
#define CBUF_BYTES (NWG * 256 * 4)                 // 262144 (c-state per WG)
#define BPS_OFF (CBUF_OFF + CBUF_BYTES)            // 3936256
#define BPS_BYTES (TSEQ * BSZ * KTAG)              // 393216
#define XP_OFF (BPS_OFF + BPS_BYTES)               // 4329472
#define XP_BYTES (64 * 4 * TPH * 32 * 32 * 4)      // 67108864; total ws ~71.5 MB

// ---------------- LSTM phase kernel LDS (float offsets) ----------------
#define LW_OFF 0        // 16384: Wh slice [e 512][32 j] quad-XOR swizzled
#define LH_OFF 16384    // 16384: h slice  [e 512][32 c] quad-XOR swizzled
#define LG_OFF 32768    // 4096 : per-wave partial gates [4][32 j][32 c]
#define LXP_OFF 36864   // 1056 : xp tile [32 c][33]
#define LHL_OFF 37920   // 256  : h local [8 uu][32 c]
#define LCS_OFF 38176   // 256  : c-state [8 uu][32 c]
#define LBI_OFF 38432   // 32   : bias
#define LWO_OFF 38464   // 96   : W_out slice [12 k][8 uu]
#define LSL_OFF 38560   // 32 ints: seq lens
#define LMX_OFF 38592   // 1 int : group max seq len
#define LSTM_SMEM_FLOATS 38596
#define LSTM_SMEM_BYTES (LSTM_SMEM_FLOATS * 4)     // 154384 < 160 KiB

// ---------------- pre-GEMM kernel LDS ----------------
#define PW_OFF 0        // 16384: Wi slice [e 512][32 j] swizzled
#define PE_OFF 16384    // 8192 : emb chunk [e 128][64 r] swizzled
#define PT_OFF 24576    // 64 ints: tokens
#define PRE_SMEM_FLOATS 24640
#define PRE_SMEM_BYTES (PRE_SMEM_FLOATS * 4)       // 98560

__device__ __forceinline__ float sigm(float x) { return 1.f / (1.f + expf(-x)); }

// flat 64-WG group barrier; cumulative epoch, flag at bar[g*64], cnt at bar[g*64+16]
__device__ __forceinline__ void gbar64(unsigned* bar, int g, unsigned epoch) {
  __syncthreads();
  if (threadIdx.x == 0) {
    __builtin_amdgcn_fence(__ATOMIC_RELEASE, "agent");
    unsigned o = __hip_atomic_fetch_add(&bar[g * 64 + 16], 1u, __ATOMIC_RELAXED,
                                        __HIP_MEMORY_SCOPE_AGENT);
    if (o == epoch * 64u - 1u) {
      __builtin_amdgcn_fence(__ATOMIC_ACQUIRE, "agent");
      __hip_atomic_store(&bar[g * 64], epoch, __ATOMIC_RELAXED, __HIP_MEMORY_SCOPE_AGENT);
    } else {
      while (__hip_atomic_load(&bar[g * 64], __ATOMIC_RELAXED, __HIP_MEMORY_SCOPE_AGENT) <
             epoch) {}
      __builtin_amdgcn_fence(__ATOMIC_ACQUIRE, "agent");
    }
  }
  __syncthreads();
}

// ---------------- init: h0 -> hbuf[0], c0 -> cbuf ----------------
__global__ void init_state(const float* __restrict__ h0, const float* __restrict__ c0,
                           float* __restrict__ hbuf, float* __restrict__ cbuf) {
  int i = blockIdx.x * 256 + threadIdx.x;
  if (i < 65536) {
    // hbuf[0][u][ch], ch = ct*32+c, dir=ct>>1, b=((ct&1)<<5)+c
    int u = i >> 7, ch = i & 127;
    int ct = ch >> 5, c = ch & 31;
    int dir = ct >> 1, b = ((ct & 1) << 5) + c;
    hbuf[i] = h0[(dir * 64 + b) * 512 + u];
  } else {
    int j = i - 65536;          // cbuf[wg][uu*32+c], wg = ct*64+ut (== blockIdx of lstm)
    int wg = j >> 8, r = j & 255;
    int ct = wg >> 6, ut = wg & 63;
    int uu = r >> 5, c = r & 31;
    int dir = ct >> 1, b = ((ct & 1) << 5) + c;
    cbuf[j] = c0[(dir * 64 + b) * 512 + ut * 8 + uu];
  }
}

// ---------------- pre-GEMM: xp[ut][ct][taul][c][j] = emb(b, pos(tau)) @ Wi_slice ----------------
// one WG: (dir,ut) x one b; 64 tau-rows x 32 j, K=512. es=8 k-split + shfl butterfly.
__global__ __launch_bounds__(256, 1) void pre_gemm(
    int phase, const int* __restrict__ sentence, const int* __restrict__ seq_lens,
    const float* __restrict__ embed, const float* __restrict__ Wi_f,
    const float* __restrict__ Wi_b, float* __restrict__ xp) {
  extern __shared__ float sm[];
  float* wiS = sm + PW_OFF;
  float* embS = sm + PE_OFF;
  int* tokS = (int*)(sm + PT_OFF);

  const int tid = threadIdx.x;
  const int dirut = blockIdx.x;            // 128
  const int dir = dirut >> 6, ut = dirut & 63;
  const int b = blockIdx.y;                // 64
  const int sl = seq_lens[b];
  const int t0 = phase * TPH;
  if (t0 >= sl) return;                    // whole tile masked out
  const int u0 = ut * 8;
  const int ct = dir * 2 + (b >> 5);
  const int cc = b & 31;
  const float* Wi = dir ? Wi_b : Wi_f;

  // Wi slice, same quad swizzle as lstm: wiS[e*32 + ((j>>2 ^ e&7)<<2 | j&3)]
  for (int j = 0; j < 32; ++j) {
    int row = (j >> 3) * 512 + u0 + (j & 7);
    for (int ee = tid; ee < 512; ee += BLK)
      wiS[ee * 32 + ((((j >> 2) ^ (ee & 7)) << 2) | (j & 3))] = Wi[row * 512 + ee];
  }
  if (tid < 64) {
    int tg = t0 + tid;
    int pos = dir ? (sl - 1 - tg) : tg;
    pos = min(max(pos, 0), 511);           // clamp; stores guarded later
    tokS[tid] = sentence[b * 512 + pos];
  }
  __syncthreads();

  const int lane = tid & 63, w = tid >> 6;
  const int es = lane >> 3, tl8 = lane & 7;
  const int tile = w * 8 + tl8;            // 32 (jt,rt) tiles
  const int jt = tile & 3, rt = tile >> 2; // rt in [0,8)
  const int rr = tid & 63, seg = tid >> 6; // staging: row rr, 32-float segment seg

  float acc[8][8];
#pragma unroll
  for (int a = 0; a < 8; ++a)
#pragma unroll
    for (int b2 = 0; b2 < 8; ++b2) acc[a][b2] = 0.f;

  const int mytok = tokS[rr];
  float4 vb[2][8];
  {
    const float* src = embed + (size_t)mytok * 512 + seg * 32;
#pragma unroll
    for (int q = 0; q < 8; ++q) vb[0][q] = *(const float4*)(src + q * 4);
  }
  const int rq = rr >> 2, rl = rr & 3;
  const float* wp0b = wiS + (((jt * 2) ^ es) << 2) + es * 32;
  const float* wp1b = wiS + (((jt * 2 + 1) ^ es) << 2) + es * 32;
  const float* ep0 = embS + es * 64 + ((((rt * 2) ^ es)) << 2);
  const float* ep1 = embS + es * 64 + ((((rt * 2 + 1) ^ es)) << 2);

#pragma unroll
  for (int kk = 0; kk < 4; ++kk) {
    if (kk) __syncthreads();               // prev compute done reading embS
#pragma unroll
    for (int q = 0; q < 8; ++q) {          // transpose-store chunk (2-way max conflict)
      const int el = seg * 32 + q * 4;
      const float4 v = vb[kk & 1][q];
      embS[(el + 0) * 64 + (((rq ^ ((el + 0) & 7)) << 2) | rl)] = v.x;
      embS[(el + 1) * 64 + (((rq ^ ((el + 1) & 7)) << 2) | rl)] = v.y;
      embS[(el + 2) * 64 + (((rq ^ ((el + 2) & 7)) << 2) | rl)] = v.z;
      embS[(el + 3) * 64 + (((rq ^ ((el + 3) & 7)) << 2) | rl)] = v.w;
    }
    if (kk < 3) {                          // prefetch next chunk during compute
      const float* src = embed + (size_t)mytok * 512 + (kk + 1) * 128 + seg * 32;
#pragma unroll
      for (int q = 0; q < 8; ++q) vb[(kk + 1) & 1][q] = *(const float4*)(src + q * 4);
    }
    __syncthreads();
    const float* wp0 = wp0b + kk * 128 * 32;
    const float* wp1 = wp1b + kk * 128 * 32;
#pragma unroll
    for (int i = 0; i < 16; ++i) {
      const float4 w0 = *(const float4*)(wp0 + i * 256);
      const float4 w1 = *(const float4*)(wp1 + i * 256);
      const float4 x0 = *(const float4*)(ep0 + i * 512);
      const float4 x1 = *(const float4*)(ep1 + i * 512);
      float wv[8] = {w0.x, w0.y, w0.z, w0.w, w1.x, w1.y, w1.z, w1.w};
      float xv[8] = {x0.x, x0.y, x0.z, x0.w, x1.x, x1.y, x1.z, x1.w};
#pragma unroll
      for (int a = 0; a < 8; ++a)
#pragma unroll
        for (int b2 = 0; b2 < 8; ++b2) acc[a][b2] = fmaf(wv[a], xv[b2], acc[a][b2]);
    }
  }

  // butterfly reduce-scatter over es lane-bits (8,16,32); all indices static
  const bool hi1 = (lane & 8) != 0;
  float r1[4][8];
#pragma unroll
  for (int a = 0; a < 4; ++a)
#pragma unroll
    for (int b2 = 0; b2 < 8; ++b2) {
      float sendv = hi1 ? acc[a][b2] : acc[a + 4][b2];
      float keepv = hi1 ? acc[a + 4][b2] : acc[a][b2];
      r1[a][b2] = keepv + __shfl_xor(sendv, 8, 64);
    }
  const bool hi2 = (lane & 16) != 0;
  float r2[4][4];
#pragma unroll
  for (int a = 0; a < 4; ++a)
#pragma unroll
    for (int b2 = 0; b2 < 4; ++b2) {
      float sendv = hi2 ? r1[a][b2] : r1[a][b2 + 4];
      float keepv = hi2 ? r1[a][b2 + 4] : r1[a][b2];
      r2[a][b2] = keepv + __shfl_xor(sendv, 16, 64);
    }
  const bool hi3 = (lane & 32) != 0;
  float r3[2][4];
#pragma unroll
  for (int a = 0; a < 2; ++a)
#pragma unroll
    for (int b2 = 0; b2 < 4; ++b2) {
      float sendv = hi3 ? r2[a][b2] : r2[a + 2][b2];
      float keepv = hi3 ? r2[a + 2][b2] : r2[a][b2];
      r3[a][b2] = keepv + __shfl_xor(sendv, 32, 64);
    }
  const int ab1 = hi1 ? 4 : 0, bb = hi2 ? 4 : 0, ab2 = hi3 ? 2 : 0;
  const size_t base = (size_t)(ut * 4 + ct) * (TPH * 1024) + (size_t)cc * 32;
#pragma unroll
  for (int a = 0; a < 2; ++a)
#pragma unroll
    for (int b2 = 0; b2 < 4; ++b2) {
      int tau = rt * 8 + bb + b2;
      if (t0 + tau < sl)
        xp[base + (size_t)tau * 1024 + (jt * 8 + ab1 + ab2 + a)] = r3[a][b2];
    }
}

// ---------------- LSTM recurrent phase (cooperative, 256 WGs) ----------------
// WG (ut,ct): 32 j-rows x 32 c-cols, K = 512 (Wh only). 4 independent ct-groups.
__global__ __launch_bounds__(BLK, 1) void lstm_phase(
    int phase, const int* __restrict__ seq_lens, const float* __restrict__ Wh_f,
    const float* __restrict__ Wh_b, const float* __restrict__ b_f,
    const float* __restrict__ b_b, const float* __restrict__ W_out,
    const float* __restrict__ xp, float* __restrict__ hbuf, float* __restrict__ cbuf,
    unsigned long long* __restrict__ featsFix, unsigned* __restrict__ bar) {
  extern __shared__ float sm[];
  float* wS = sm + LW_OFF;
  float* hS = sm + LH_OFF;
  float* gS = sm + LG_OFF;
  float* xpS = sm + LXP_OFF;
  float* hlS = sm + LHL_OFF;
  float* cstS = sm + LCS_OFF;
  float* biasS = sm + LBI_OFF;
  float* woutS = sm + LWO_OFF;
  int* slS = (int*)(sm + LSL_OFF);
  int* mslS = (int*)(sm + LMX_OFF);

  const int tid = threadIdx.x;
  const int bid = blockIdx.x;
  const int ut = bid & 63, ct = bid >> 6;
  const int u0 = ut * 8, ch0 = ct * 32, dir = ct >> 1;
  const float* Wh = dir ? Wh_b : Wh_f;
  const float* bb = dir ? b_b : b_f;

  if (tid < 32) slS[tid] = seq_lens[((ct & 1) << 5) + tid];
  __syncthreads();
  if (tid == 0) {
    int m = 0;
    for (int c = 0; c < 32; ++c) m = max(m, slS[c]);
    *mslS = m;
  }
  __syncthreads();
  const int gmax = *mslS;
  const int t0 = phase * TPH;
  if (t0 >= gmax) return;                  // whole group done (uniform per ct-group)

  // Wh slice, quad swizzle
  for (int j = 0; j < 32; ++j) {
    int row = (j >> 3) * 512 + u0 + (j & 7);
    for (int ee = tid; ee < 512; ee += BLK)
      wS[ee * 32 + ((((j >> 2) ^ (ee & 7)) << 2) | (j & 3))] = Wh[row * 512 + ee];
  }
  if (tid < 96) woutS[tid] = W_out[(tid >> 3) * 1024 + dir * 512 + u0 + (tid & 7)];
  if (tid < 32) biasS[tid] = bb[(tid >> 3) * 512 + u0 + (tid & 7)];
  cstS[tid] = cbuf[bid * 256 + tid];
  __syncthreads();

  const int lane = tid & 63, w = tid >> 6;
  const int tp = lane & 15, jt = tp & 3, ct2 = tp >> 2;
  const int es = w * 4 + (lane >> 4);      // k-split 16; e = i*16 + es
  const int esw = es & 7;                  // constant per thread (16 % 8 == 0)
  const int nst = min(TPH, gmax - t0);

  const float* wpA = wS + es * 32 + (((jt * 2) ^ esw) << 2);
  const float* wpB = wS + es * 32 + (((jt * 2 + 1) ^ esw) << 2);
  const float* hpA = hS + es * 32 + (((ct2 * 2) ^ esw) << 2);
  const float* hpB = hS + es * 32 + (((ct2 * 2 + 1) ^ esw) << 2);

  // prefetch xp tile for first step (4 KB contiguous per WG per step)
  float4 xr = *(const float4*)(xp + ((size_t)(ut * 4 + ct) * TPH + 0) * 1024 + tid * 4);

  for (int tl = 0; tl < nst; ++tl) {
    const int t = t0 + tl;
    const float* hcur = hbuf + (t & 1) * 65536;
    float* hnxt = hbuf + ((t + 1) & 1) * 65536;

    // [A] bulk-stage h slice -> LDS (swizzled), store xp regs, prefetch next xp
#pragma unroll
    for (int it = 0; it < 16; ++it) {
      int u = it * 32 + (tid >> 3), q = tid & 7;
      float4 hv = *(const float4*)(hcur + u * 128 + ch0 + q * 4);
      *(float4*)(hS + u * 32 + ((q ^ (u & 7)) << 2)) = hv;
    }
    {
      int c = tid >> 3, j4 = tid & 7;
      float* d = xpS + c * 33 + j4 * 4;    // stride 33: conflict-free epilogue reads
      d[0] = xr.x; d[1] = xr.y; d[2] = xr.z; d[3] = xr.w;
    }
    if (tl + 1 < nst)
      xr = *(const float4*)(xp + ((size_t)(ut * 4 + ct) * TPH + (tl + 1)) * 1024 + tid * 4);
    __syncthreads();

    // [B] 32x32x512 matmul: 8x8 register tile, zero mid-loop syncs
    float acc[8][8];
#pragma unroll
    for (int a = 0; a < 8; ++a)
#pragma unroll
      for (int b2 = 0; b2 < 8; ++b2) acc[a][b2] = 0.f;
    for (int io = 0; io < 4; ++io) {
#pragma unroll
      for (int ii = 0; ii < 8; ++ii) {
        const int off = (io * 8 + ii) * 512;   // e advances by 16 -> 512 floats
        const float4 w0 = *(const float4*)(wpA + off);
        const float4 w1 = *(const float4*)(wpB + off);
        const float4 x0 = *(const float4*)(hpA + off);
        const float4 x1 = *(const float4*)(hpB + off);
        float wv[8] = {w0.x, w0.y, w0.z, w0.w, w1.x, w1.y, w1.z, w1.w};
        float xv[8] = {x0.x, x0.y, x0.z, x0.w, x1.x, x1.y, x1.z, x1.w};
#pragma unroll
        for (int a = 0; a < 8; ++a)
#pragma unroll
          for (int b2 = 0; b2 < 8; ++b2) acc[a][b2] = fmaf(wv[a], xv[b2], acc[a][b2]);
      }
    }

    // in-wave butterfly reduce-scatter over es lane-bits 16,32 (no LDS tree)
    const bool hi1 = (lane & 16) != 0;
    float r1[4][8];
#pragma unroll
    for (int a = 0; a < 4; ++a)
#pragma unroll
      for (int b2 = 0; b2 < 8; ++b2) {
        float sendv = hi1 ? acc[a][b2] : acc[a + 4][b2];
        float keepv = hi1 ? acc[a + 4][b2] : acc[a][b2];
        r1[a][b2] = keepv + __shfl_xor(sendv, 16, 64);
      }
    const bool hi2 = (lane & 32) != 0;
    float r2[4][4];
#pragma unroll
    for (int a = 0; a < 4; ++a)
#pragma unroll
      for (int b2 = 0; b2 < 4; ++b2) {
        float sendv = hi2 ? r1[a][b2] : r1[a][b2 + 4];
        float keepv = hi2 ? r1[a][b2 + 4] : r1[a][b2];
        r2[a][b2] = keepv + __shfl_xor(sendv, 32, 64);
      }
    const int ab = hi1 ? 4 : 0, bbs = hi2 ? 4 : 0;
#pragma unroll
    for (int a = 0; a < 4; ++a) {
      float4 v = make_float4(r2[a][0], r2[a][1], r2[a][2], r2[a][3]);
      *(float4*)(gS + w * 1024 + (jt * 8 + ab + a) * 32 + ct2 * 8 + bbs) = v;
    }
    __syncthreads();

    // [C] epilogue: combine 4 wave-partials + xp + bias -> gates -> c,h
    {
      const int uu = tid >> 5, c = tid & 31;
      const int slc = slS[c];
      float s0 = 0.f, s1 = 0.f, s2 = 0.f, s3 = 0.f;
#pragma unroll
      for (int w2 = 0; w2 < 4; ++w2) {
        const float* gp = gS + w2 * 1024 + uu * 32 + c;
        s0 += gp[0];
        s1 += gp[256];
        s2 += gp[512];
        s3 += gp[768];
      }
      const bool xvalid = (t < slc);
      float x0 = xvalid ? xpS[c * 33 + uu] : 0.f;
      float x1 = xvalid ? xpS[c * 33 + 8 + uu] : 0.f;
      float x2 = xvalid ? xpS[c * 33 + 16 + uu] : 0.f;
      float x3 = xvalid ? xpS[c * 33 + 24 + uu] : 0.f;
      float iv = s0 + x0 + biasS[uu];
      float fv = s1 + x1 + biasS[8 + uu];
      float gv = s2 + x2 + biasS[16 + uu];
      float ov = s3 + x3 + biasS[24 + uu];
      float cn = sigm(fv) * cstS[uu * 32 + c] + sigm(iv) * tanhf(gv);
      float hn = sigm(ov) * tanhf(cn);
      cstS[uu * 32 + c] = cn;
      hnxt[(u0 + uu) * 128 + ch0 + c] = hn;
      hlS[uu * 32 + c] = hn;
    }
    __syncthreads();

    // feats partial: fixed-point atomics (deterministic across 128 contributing WGs)
    for (int base = 0; base < 384; base += 256) {
      int idx = base + tid;
      if (idx < 384) {
        int c = idx / 12, k = idx % 12;
        int sl = slS[c];
        if (t < sl) {
          float pacc = 0.f;
#pragma unroll
          for (int uu = 0; uu < 8; ++uu) pacc += hlS[uu * 32 + c] * woutS[k * 8 + uu];
          int tt = dir ? (sl - 1 - t) : t;
          double y = (double)pacc * FIX_SCALE;
          long long q = (long long)(y + (y >= 0.0 ? 0.5 : -0.5));
          atomicAdd(&featsFix[((size_t)(((ct & 1) << 5) + c) * 512 + tt) * 12 + k],
                    (unsigned long long)q);
        }
      }
    }
    gbar64(bar, ct, (unsigned)(t + 1));    // only the 64 WGs sharing ct
  }
  cbuf[bid * 256 + tid] = cstS[tid];       // carry c-state to next phase
}

// ---------------- viterbi (unchanged) ----------------
__global__ __launch_bounds__(768) void viterbi_kernel(
    const int* __restrict__ seq_lens, const float* __restrict__ b_out,
    const float* __restrict__ transitions,
    const unsigned long long* __restrict__ featsFix,
    unsigned char* __restrict__ bps, float* __restrict__ out) {
  __shared__ float fvL[64 * 13];
  __shared__ float tmL[64 * 13];
  __shared__ float trL[144];
  __shared__ float boutL[12];
  __shared__ int slL[64];
  __shared__ unsigned char tagL[64 * 512];
  const int tid = threadIdx.x;
  const int b = tid & 63, k = tid >> 6;
  if (tid < 144) trL[tid] = transitions[tid];
  if (tid < 12) boutL[tid] = b_out[tid];
  if (tid < 64) slL[tid] = seq_lens[tid];
  fvL[b * 13 + k] = (k == START_TAG) ? 0.f : -10000.f;
  __syncthreads();
  for (int t = 0; t < TSEQ; ++t) {
    bool m = t < slL[b];
    float best = fvL[b * 13 + 0] + trL[k * 12 + 0];
    int arg = 0;
#pragma unroll
    for (int p = 1; p < 12; ++p) {
      float v = fvL[b * 13 + p] + trL[k * 12 + p];
      if (v > best) { best = v; arg = p; }
    }
    long long fx = (long long)featsFix[((size_t)b * 512 + t) * 12 + k];
    float feat = (float)((double)fx * FIX_INV) + boutL[k];
    float nv = m ? (best + feat) : fvL[b * 13 + k];
    bps[((size_t)t * 64 + b) * 12 + k] = (unsigned char)(m ? arg : k);
    __syncthreads();
    fvL[b * 13 + k] = nv;
    __syncthreads();
  }
  tmL[b * 13 + k] = fvL[b * 13 + k] + trL[STOP_TAG * 12 + k];
  __syncthreads();
  if (tid < 64) {
    float best = tmL[tid * 13 + 0];
    int arg = 0;
    for (int kk = 1; kk < 12; ++kk) {
      float v = tmL[tid * 13 + kk];
      if (v > best) { best = v; arg = kk; }
    }
    out[tid] = best;
    int tag = arg;
    const uint32_t* rowp = (const uint32_t*)bps;
    uint32_t r0, r1, r2;
    { int off = (511 * 64 + tid) * 3; r0 = rowp[off]; r1 = rowp[off + 1]; r2 = rowp[off + 2]; }
    for (int t = 511; t >= 0; --t) {
      uint32_t n0 = 0, n1 = 0, n2 = 0;
      if (t > 0) {
        int off = ((t - 1) * 64 + tid) * 3;
        n0 = rowp[off]; n1 = rowp[off + 1]; n2 = rowp[off + 2];
      }
      tagL[tid * 512 + t] = (unsigned char)tag;
      uint32_t sel = (tag < 4) ? (r0 >> (tag * 8))
                   : (tag < 8) ? (r1 >> ((tag - 4) * 8))
                               : (r2 >> ((tag - 8) * 8));
      tag = (int)(sel & 0xffu);
      r0 = n0; r1 = n1; r2 = n2;
    }
  }
  __syncthreads();
  for (int idx = tid; idx < 64 * 512; idx += 768)
    out[64 + idx] = (float)tagL[idx];
}

extern "C" void kernel_launch(void* const* d_in, const int* in_sizes, int n_in,
                              void* d_out, int out_size, void* d_ws, size_t ws_size,
                              hipStream_t stream) {
  (void)in_sizes; (void)n_in; (void)out_size; (void)ws_size;
  const int* sentence = (const int*)d_in[0];
  const int* seq_lens = (const int*)d_in[1];
  const float* embed = (const float*)d_in[2];
  const float* Wi_f = (const float*)d_in[3];
  const float* Wh_f = (const float*)d_in[4];
  const float* b_f = (const float*)d_in[5];
  const float* Wi_b = (const float*)d_in[6];
  const float* Wh_b = (const float*)d_in[7];
  const float* b_b = (const float*)d_in[8];
  const float* h0 = (const float*)d_in[9];
  const float* c0 = (const float*)d_in[10];
  const float* W_out = (const float*)d_in[11];
  const float* b_out = (const float*)d_in[12];
  const float* trans = (const float*)d_in[13];

  char* ws = (char*)d_ws;
  unsigned* bar = (unsigned*)ws;
  unsigned long long* featsFix = (unsigned long long*)(ws + FEATS_OFF);
  float* hbuf = (float*)(ws + HBUF_OFF);
  float* cbuf = (float*)(ws + CBUF_OFF);
  unsigned char* bps = (unsigned char*)(ws + BPS_OFF);
  float* xpw = (float*)(ws + XP_OFF);

  hipMemsetAsync(d_ws, 0, FEATS_OFF + FEATS_BYTES, stream);  // bar + feats only

  hipFuncSetAttribute((const void*)lstm_phase,
                      hipFuncAttributeMaxDynamicSharedMemorySize, LSTM_SMEM_BYTES);
  hipFuncSetAttribute((const void*)pre_gemm,
                      hipFuncAttributeMaxDynamicSharedMemorySize, PRE_SMEM_BYTES);

  init_state<<<dim3(512), dim3(256), 0, stream>>>(h0, c0, hbuf, cbuf);

  for (int p = 0; p < NPH; ++p) {
    pre_gemm<<<dim3(128, 64), dim3(BLK), PRE_SMEM_BYTES, stream>>>(
        p, sentence, seq_lens, embed, Wi_f, Wi_b, xpw);
    int pv = p;
    void* kargs[] = {(void*)&pv,    (void*)&seq_lens, (void*)&Wh_f, (void*)&Wh_b,
                     (void*)&b_f,   (void*)&b_b,      (void*)&W_out, (void*)&xpw,
                     (void*)&hbuf,  (void*)&cbuf,     (void*)&featsFix, (void*)&bar};
    hipLaunchCooperativeKernel((const void*)lstm_phase, dim3(NWG), dim3(BLK), kargs,
                               LSTM_SMEM_BYTES, stream);
  }
  viterbi_kernel<<<dim3(1), dim3(768), 0, stream>>>(seq_lens, b_out, trans, featsFix,
                                                    bps, (float*)d_out);
}